// Round 4
// baseline (6761.135 us; speedup 1.0000x reference)
//
#include <hip/hip_runtime.h>
#include <math.h>

// Problem constants
#define Bq 8
#define Nq 8192
#define Dq 256
#define Qq 4
#define Kq 2048
#define Mq (Nq / Qq)
#define TT (Bq * Nq)                    // 65536 tokens
#define QUANT_ELEMS ((size_t)TT * Dq)   // 16777216

// GEMM tiling
#define GT 64           // tokens per block (M)
#define GC 256          // codes per c0 tile (N)
#define XPITCH 264      // bf16 units per x row (256 + 8 pad)
#define EPITCH 72       // bf16 units per e chunk row (64 + 8 pad)

#define CAP1 16384
#define CAP2 4096
#define THRESH1 1.2e-3f
#define THRESH2 3e-5f

// ws layout (bytes)
#define WS_INVE_OFF   0u          // 8192 floats
#define WS_INVX_OFF   32768u      // 65536 floats
#define WS_CNT_OFF    294912u     // cnt1 @ +0, cnt2 @ +4
#define WS_LIST1_OFF  294928u     // CAP1 ints
#define WS_LIST2_OFF  360464u     // CAP2 ints
#define WS_ENB_OFF    393216u     // 4*4*2048*72 bf16 = 4718592 B

typedef __attribute__((ext_vector_type(8))) short    bf16x8;
typedef __attribute__((ext_vector_type(4))) float    f32x4;
typedef __attribute__((ext_vector_type(8))) unsigned short u16x8;

__device__ __forceinline__ unsigned short f2bf(float f) {
    union { float f; unsigned u; } v; v.f = f;
    unsigned r = v.u + 0x7fffu + ((v.u >> 16) & 1u);
    return (unsigned short)(r >> 16);
}

__device__ __forceinline__ void async_load16(const void* g, void* s) {
    __builtin_amdgcn_global_load_lds(
        (const __attribute__((address_space(1))) void*)g,
        (__attribute__((address_space(3))) void*)s, 16, 0, 0);
}

// ---------------- inverse norms of rows (one wave per row, 4 rows/block) ----
__global__ __launch_bounds__(256) void norm_kernel(const float* __restrict__ src,
                                                   float* __restrict__ inv) {
    int row  = blockIdx.x * 4 + (threadIdx.x >> 6);
    int lane = threadIdx.x & 63;
    float4 v = *(const float4*)(src + (size_t)row * Dq + lane * 4);
    float s = v.x * v.x + v.y * v.y + v.z * v.z + v.w * v.w;
    #pragma unroll
    for (int off = 32; off; off >>= 1) s += __shfl_down(s, off, 64);
    if (lane == 0) inv[row] = 1.0f / fmaxf(sqrtf(s), 1e-12f);
}

// ---------------- normalized embed -> bf16, pre-chunked padded layout -------
// enb[(q*4+ch)*2048 + code][72]: 64 bf16 of dims [ch*64, ch*64+64) + 8 pad
__global__ __launch_bounds__(256) void cvt_kernel(const float* __restrict__ embed,
                                                  const float* __restrict__ inv_e,
                                                  unsigned short* __restrict__ enb) {
    int row  = blockIdx.x * 4 + (threadIdx.x >> 6);   // 0..8191
    int lane = threadIdx.x & 63;
    int q = row >> 11, code = row & 2047;
    float sc = inv_e[row];
    float4 v = *(const float4*)(embed + (size_t)row * Dq + lane * 4);
    int ch = lane >> 4;               // which 64-dim chunk
    int dc = (lane * 4) & 63;         // offset within chunk
    unsigned short* dst = enb + ((size_t)((q * 4 + ch) * 2048 + code)) * EPITCH + dc;
    ushort4 p;
    p.x = f2bf(v.x * sc); p.y = f2bf(v.y * sc);
    p.z = f2bf(v.z * sc); p.w = f2bf(v.w * sc);
    *(ushort4*)dst = p;
}

// ---------------- stage 1: bf16 MFMA scoring + top-2 + gather ---------------
__global__ __launch_bounds__(256, 2) void gemm_kernel(const float* __restrict__ x,
                                                      const float* __restrict__ embed,
                                                      const unsigned short* __restrict__ enb,
                                                      const float* __restrict__ inv_x,
                                                      float* __restrict__ out,
                                                      int* __restrict__ cnt1,
                                                      int* __restrict__ list1) {
    __shared__ __align__(16) unsigned short xs[GT * XPITCH];   // 33792 B
    __shared__ __align__(16) unsigned short es[GC * EPITCH];   // 36864 B
    __shared__ float rb1[4][GT];
    __shared__ float rb2[4][GT];
    __shared__ int   rix[4][GT];
    __shared__ int   sIdx[GT];

    const int tid = threadIdx.x;
    const int wv  = tid >> 6;
    const int ln  = tid & 63;
    const int quad = ln >> 4;
    const int l15  = ln & 15;

    // XCD swizzle: one codebook per XCD's L2
    const int bid  = blockIdx.x;
    const int q    = (bid & 7) >> 1;
    const int tile = ((bid >> 3) << 1) | (bid & 1);
    const int t0   = (tile >> 5) * Nq + q * Mq + (tile & 31) * GT;

    // ---- stage x tile once: fp32 -> normalize -> bf16 -> LDS --------------
    {
        int m = tid >> 2;
        int dseg = (tid & 3) * 64;
        float sx = inv_x[t0 + m];
        const float* xr = x + (size_t)(t0 + m) * Dq + dseg;
        unsigned short* xd = xs + m * XPITCH + dseg;
        #pragma unroll
        for (int i = 0; i < 8; ++i) {
            float4 a = *(const float4*)(xr + i * 8);
            float4 b = *(const float4*)(xr + i * 8 + 4);
            u16x8 p;
            p[0] = f2bf(a.x * sx); p[1] = f2bf(a.y * sx);
            p[2] = f2bf(a.z * sx); p[3] = f2bf(a.w * sx);
            p[4] = f2bf(b.x * sx); p[5] = f2bf(b.y * sx);
            p[6] = f2bf(b.z * sx); p[7] = f2bf(b.w * sx);
            *(u16x8*)(xd + i * 8) = p;
        }
    }

    float run1[16], run2[16];
    int   runi[16];
    #pragma unroll
    for (int e = 0; e < 16; ++e) { run1[e] = -2.0f; run2[e] = -2.0f; runi[e] = 0; }

    for (int c0 = 0; c0 < Kq; c0 += GC) {
        f32x4 acc[4][4];
        #pragma unroll
        for (int mf = 0; mf < 4; ++mf)
            #pragma unroll
            for (int nf = 0; nf < 4; ++nf)
                acc[mf][nf] = (f32x4){0.f, 0.f, 0.f, 0.f};

        for (int ch = 0; ch < 4; ++ch) {
            __syncthreads();   // previous chunk fully consumed
            // async stage e chunk: 36864 B, 9 x 1KB per wave
            const unsigned short* gsrc =
                enb + ((size_t)((q * 4 + ch) * 2048 + c0)) * EPITCH;
            #pragma unroll
            for (int i = 0; i < 9; ++i) {
                int off = (wv * 9 + i) * 1024;
                async_load16((const char*)gsrc + off + ln * 16, (char*)es + off);
            }
            __syncthreads();   // compiler drains vmcnt before s_barrier

            #pragma unroll
            for (int ks = 0; ks < 2; ++ks) {
                bf16x8 af[4], bfr[4];
                #pragma unroll
                for (int mf = 0; mf < 4; ++mf)
                    af[mf] = *(const bf16x8*)(xs + (mf * 16 + l15) * XPITCH
                                              + ch * 64 + ks * 32 + quad * 8);
                #pragma unroll
                for (int nf = 0; nf < 4; ++nf)
                    bfr[nf] = *(const bf16x8*)(es + (wv * 64 + nf * 16 + l15) * EPITCH
                                               + ks * 32 + quad * 8);
                #pragma unroll
                for (int mf = 0; mf < 4; ++mf)
                    #pragma unroll
                    for (int nf = 0; nf < 4; ++nf)
                        acc[mf][nf] = __builtin_amdgcn_mfma_f32_16x16x32_bf16(
                            af[mf], bfr[nf], acc[mf][nf], 0, 0, 0);
            }
        }

        // merge this c0 tile into per-lane running top-2 (cols ascend: nf, c0)
        const int cb = c0 + wv * 64 + l15;
        #pragma unroll
        for (int mf = 0; mf < 4; ++mf)
            #pragma unroll
            for (int r = 0; r < 4; ++r) {
                const int e = mf * 4 + r;
                #pragma unroll
                for (int nf = 0; nf < 4; ++nf) {
                    float s = acc[mf][nf][r];
                    int   c = cb + nf * 16;
                    if (s > run1[e]) { run2[e] = run1[e]; run1[e] = s; runi[e] = c; }
                    else if (s > run2[e]) { run2[e] = s; }
                }
            }
    }

    // cross-lane reduce within 16-lane groups, then stash per-wave results
    #pragma unroll
    for (int e = 0; e < 16; ++e) {
        float b1 = run1[e], b2 = run2[e]; int ix = runi[e];
        #pragma unroll
        for (int m = 1; m < 16; m <<= 1) {
            float o1 = __shfl_xor(b1, m, 64);
            float o2 = __shfl_xor(b2, m, 64);
            int   oi = __shfl_xor(ix, m, 64);
            if (o1 > b1 || (o1 == b1 && oi < ix)) { b2 = fmaxf(b1, o2); b1 = o1; ix = oi; }
            else { b2 = fmaxf(b2, fmaxf(o1, o2) == o1 ? o1 : o1); b2 = fmaxf(b2, o1); }
        }
        if (l15 == 0) {
            int m = (e >> 2) * 16 + quad * 4 + (e & 3);
            rb1[wv][m] = b1; rb2[wv][m] = b2; rix[wv][m] = ix;
        }
    }
    __syncthreads();

    if (tid < GT) {
        float b1 = rb1[0][tid], b2 = rb2[0][tid]; int ix = rix[0][tid];
        #pragma unroll
        for (int w = 1; w < 4; ++w) {
            float o1 = rb1[w][tid], o2 = rb2[w][tid]; int oi = rix[w][tid];
            if (o1 > b1 || (o1 == b1 && oi < ix)) { b2 = fmaxf(b1, o2); b1 = o1; ix = oi; }
            else { b2 = fmaxf(b2, o1); }
        }
        int t = t0 + tid;
        out[QUANT_ELEMS + (size_t)t] = (float)ix;
        sIdx[tid] = ix;
        if (b1 - b2 < THRESH1) {
            int pos = atomicAdd(cnt1, 1);
            if (pos < CAP1) list1[pos] = t;
        }
    }
    __syncthreads();

    // gather raw embed rows -> quantized output
    const float* eq = embed + (size_t)q * Kq * Dq;
    #pragma unroll 4
    for (int kk = 0; kk < 16; ++kk) {
        int f = kk * 256 + tid;       // 0..4095
        int r = f >> 6, col = f & 63;
        float4 v = *(const float4*)(eq + (size_t)sIdx[r] * Dq + col * 4);
        *(float4*)(out + (size_t)(t0 + r) * Dq + col * 4) = v;
    }
    if (bid == 0 && tid == 0) out[QUANT_ELEMS + TT] = 0.0f;
}

// ---------------- stage 2: fp32 re-rank of stage-1 near-ties ----------------
__global__ __launch_bounds__(256) void rerank32(const float* __restrict__ x,
                                                const float* __restrict__ embed,
                                                const float* __restrict__ inv_e,
                                                const float* __restrict__ inv_x,
                                                float* __restrict__ out,
                                                const int* __restrict__ cnt1,
                                                const int* __restrict__ list1,
                                                int* __restrict__ cnt2,
                                                int* __restrict__ list2) {
    __shared__ float xn[Dq];
    __shared__ float sb1[256], sb2[256];
    __shared__ int   sbi[256];
    __shared__ int   s_take;
    int count = *cnt1; if (count > CAP1) count = CAP1;
    const int tid = threadIdx.x;

    for (int ii = blockIdx.x; ii < count; ii += gridDim.x) {
        int t = list1[ii];
        int q = (t % Nq) / Mq;
        const float* eq   = embed + (size_t)q * Kq * Dq;
        const float* invq = inv_e + q * Kq;
        xn[tid] = x[(size_t)t * Dq + tid] * inv_x[t];
        __syncthreads();

        float b1 = -2.0f, b2 = -2.0f; int bi = 0;
        #pragma unroll 1
        for (int j = 0; j < 8; ++j) {
            int k = tid + 256 * j;            // ascending within thread
            const float* er = eq + (size_t)k * Dq;
            float s0 = 0.f, s1 = 0.f, s2 = 0.f, s3 = 0.f;
            for (int d = 0; d < Dq; d += 4) {
                float4 ev = *(const float4*)(er + d);
                s0 = fmaf(xn[d],     ev.x, s0);
                s1 = fmaf(xn[d + 1], ev.y, s1);
                s2 = fmaf(xn[d + 2], ev.z, s2);
                s3 = fmaf(xn[d + 3], ev.w, s3);
            }
            float s = ((s0 + s1) + (s2 + s3)) * invq[k];
            if (s > b1) { b2 = b1; b1 = s; bi = k; }
            else if (s > b2) { b2 = s; }
        }
        sb1[tid] = b1; sb2[tid] = b2; sbi[tid] = bi;
        __syncthreads();
        for (int off = 128; off; off >>= 1) {
            if (tid < off) {
                float o1 = sb1[tid + off], o2 = sb2[tid + off]; int oi = sbi[tid + off];
                float a1 = sb1[tid], a2 = sb2[tid]; int ai = sbi[tid];
                if (o1 > a1 || (o1 == a1 && oi < ai)) {
                    sb2[tid] = fmaxf(a1, o2); sb1[tid] = o1; sbi[tid] = oi;
                } else {
                    sb2[tid] = fmaxf(a2, o1);
                }
            }
            __syncthreads();
        }
        if (tid == 0) {
            if (sb1[0] - sb2[0] < THRESH2) {
                int pos = atomicAdd(cnt2, 1);
                if (pos < CAP2) list2[pos] = t;
                s_take = 0;
            } else {
                out[QUANT_ELEMS + (size_t)t] = (float)sbi[0];
                s_take = 1;
            }
        }
        __syncthreads();
        if (s_take && tid < 64) {
            float4 v = *(const float4*)(eq + (size_t)sbi[0] * Dq + tid * 4);
            *(float4*)(out + (size_t)t * Dq + tid * 4) = v;
        }
        __syncthreads();
    }
}

// ---------------- numpy-fp32 emulation helpers ------------------------------
__device__ __forceinline__ float np_pw128_sq(const float* a) {
#pragma clang fp contract(off)
    float r[8];
    #pragma unroll
    for (int j = 0; j < 8; ++j) { float v = a[j]; r[j] = v * v; }
    for (int i = 8; i < 128; i += 8) {
        #pragma unroll
        for (int j = 0; j < 8; ++j) { float v = a[i + j]; r[j] = r[j] + v * v; }
    }
    return ((r[0] + r[1]) + (r[2] + r[3])) + ((r[4] + r[5]) + (r[6] + r[7]));
}
__device__ __forceinline__ float f32_div(float a, float b) {
    return (float)((double)a / (double)b);
}
__device__ __forceinline__ float np_norm256(const float* a) {
#pragma clang fp contract(off)
    float n2 = np_pw128_sq(a) + np_pw128_sq(a + 128);
    float nm = (float)sqrt((double)n2);
    return fmaxf(nm, 1e-12f);
}

// ---------------- stage 3: numpy-fp32-emulating re-rank ---------------------
__global__ __launch_bounds__(256) void fixup_np(const float* __restrict__ x,
                                                const float* __restrict__ embed,
                                                float* __restrict__ out,
                                                const int* __restrict__ cnt2,
                                                const int* __restrict__ list2) {
#pragma clang fp contract(off)
    __shared__ float xn[Dq];
    __shared__ float ssc[256];
    __shared__ int   sid[256];
    __shared__ float s_nm;
    int count = *cnt2; if (count > CAP2) count = CAP2;
    const int tid = threadIdx.x;

    for (int i = blockIdx.x; i < count; i += gridDim.x) {
        int t = list2[i];
        int q = (t % Nq) / Mq;
        const float* xr  = x + (size_t)t * Dq;
        const float* eqb = embed + (size_t)q * Kq * Dq;

        if (tid == 0) s_nm = np_norm256(xr);
        __syncthreads();
        xn[tid] = f32_div(xr[tid], s_nm);
        __syncthreads();

        float bs = -2.0f; int bk = 0;
        #pragma unroll 1
        for (int j = 0; j < 8; ++j) {
            int k = tid * 8 + j;
            const float* er = eqb + (size_t)k * Dq;
            float nme = np_norm256(er);
            float l0 = 0.0f, l1 = 0.0f, l2 = 0.0f, l3 = 0.0f;
            for (int d = 0; d < Dq; d += 4) {
                float e0 = f32_div(er[d + 0], nme);
                float e1 = f32_div(er[d + 1], nme);
                float e2 = f32_div(er[d + 2], nme);
                float e3 = f32_div(er[d + 3], nme);
                l0 = l0 + xn[d + 0] * e0;
                l1 = l1 + xn[d + 1] * e1;
                l2 = l2 + xn[d + 2] * e2;
                l3 = l3 + xn[d + 3] * e3;
            }
            float sc = (l0 + l1) + (l2 + l3);
            if (sc > bs) { bs = sc; bk = k; }
        }
        ssc[tid] = bs; sid[tid] = bk;
        __syncthreads();
        for (int off = 128; off; off >>= 1) {
            if (tid < off) {
                float os = ssc[tid + off]; int oi = sid[tid + off];
                if (os > ssc[tid] || (os == ssc[tid] && oi < sid[tid])) {
                    ssc[tid] = os; sid[tid] = oi;
                }
            }
            __syncthreads();
        }
        int kbest = sid[0];
        if (tid == 0) out[QUANT_ELEMS + (size_t)t] = (float)kbest;
        if (tid < 64) {
            float4 v = *(const float4*)(eqb + (size_t)kbest * Dq + tid * 4);
            *(float4*)(out + (size_t)t * Dq + tid * 4) = v;
        }
        __syncthreads();
    }
}

extern "C" void kernel_launch(void* const* d_in, const int* in_sizes, int n_in,
                              void* d_out, int out_size, void* d_ws, size_t ws_size,
                              hipStream_t stream) {
    const float* x     = (const float*)d_in[0];
    const float* embed = (const float*)d_in[1];
    float* out = (float*)d_out;
    char* ws = (char*)d_ws;
    float* inv_e = (float*)(ws + WS_INVE_OFF);
    float* inv_x = (float*)(ws + WS_INVX_OFF);
    int* cnt1 = (int*)(ws + WS_CNT_OFF);
    int* cnt2 = (int*)(ws + WS_CNT_OFF + 4);
    int* list1 = (int*)(ws + WS_LIST1_OFF);
    int* list2 = (int*)(ws + WS_LIST2_OFF);
    unsigned short* enb = (unsigned short*)(ws + WS_ENB_OFF);

    hipMemsetAsync(ws + WS_CNT_OFF, 0, 16, stream);
    norm_kernel<<<(Qq * Kq) / 4, 256, 0, stream>>>(embed, inv_e);
    norm_kernel<<<TT / 4, 256, 0, stream>>>(x, inv_x);
    cvt_kernel<<<(Qq * Kq) / 4, 256, 0, stream>>>(embed, inv_e, enb);
    gemm_kernel<<<TT / GT, 256, 0, stream>>>(x, embed, enb, inv_x, out, cnt1, list1);
    rerank32<<<1024, 256, 0, stream>>>(x, embed, inv_e, inv_x, out,
                                       cnt1, list1, cnt2, list2);
    fixup_np<<<256, 256, 0, stream>>>(x, embed, out, cnt2, list2);
}

// Round 5
// 950.706 us; speedup vs baseline: 7.1117x; 7.1117x over previous
//
#include <hip/hip_runtime.h>
#include <math.h>

// Problem constants
#define Bq 8
#define Nq 8192
#define Dq 256
#define Qq 4
#define Kq 2048
#define Mq (Nq / Qq)
#define TT (Bq * Nq)                    // 65536 tokens
#define QUANT_ELEMS ((size_t)TT * Dq)   // 16777216

#define CAP1Q 8192
#define CAP2  4096
#define THRESH1 1.2e-3f
#define THRESH2 3e-5f

// ws layout (bytes)
#define WS_INVE_OFF   0u          // 8192 floats
#define WS_INVX_OFF   32768u      // 65536 floats
#define WS_CNT_OFF    294912u     // cnt1[4] @ +0, cnt2 @ +16 (memset 32 B)
#define WS_LIST1_OFF  294944u     // 4 * CAP1Q ints = 128 KB
#define WS_LIST2_OFF  426016u     // CAP2 ints
#define WS_ENB_OFF    442880u     // 4*2048*256 bf16 = 4 MB (512-aligned)

typedef __attribute__((ext_vector_type(8))) short bf16x8;
typedef __attribute__((ext_vector_type(4))) float f32x4;

__device__ __forceinline__ unsigned short f2bf(float f) {
    union { float f; unsigned u; } v; v.f = f;
    unsigned r = v.u + 0x7fffu + ((v.u >> 16) & 1u);
    return (unsigned short)(r >> 16);
}

// ---------------- inverse norms of rows (one wave per row, 4 rows/block) ----
__global__ __launch_bounds__(256) void norm_kernel(const float* __restrict__ src,
                                                   float* __restrict__ inv) {
    int row  = blockIdx.x * 4 + (threadIdx.x >> 6);
    int lane = threadIdx.x & 63;
    float4 v = *(const float4*)(src + (size_t)row * Dq + lane * 4);
    float s = v.x * v.x + v.y * v.y + v.z * v.z + v.w * v.w;
    #pragma unroll
    for (int off = 32; off; off >>= 1) s += __shfl_down(s, off, 64);
    if (lane == 0) inv[row] = 1.0f / fmaxf(sqrtf(s), 1e-12f);
}

// ---------------- normalized embed -> bf16, plain [q][code][dim] ------------
__global__ __launch_bounds__(256) void cvt_kernel(const float* __restrict__ embed,
                                                  const float* __restrict__ inv_e,
                                                  unsigned short* __restrict__ enb) {
    int row  = blockIdx.x * 4 + (threadIdx.x >> 6);   // 0..8191
    int lane = threadIdx.x & 63;
    float sc = inv_e[row];
    float4 v = *(const float4*)(embed + (size_t)row * Dq + lane * 4);
    ushort4 p;
    p.x = f2bf(v.x * sc); p.y = f2bf(v.y * sc);
    p.z = f2bf(v.z * sc); p.w = f2bf(v.w * sc);
    *(ushort4*)(enb + (size_t)row * Dq + lane * 4) = p;
}

// ---------------- stage 1: barrier-free per-wave MFMA scoring ---------------
// One 64-lane wave owns 32 tokens; A (32x256 bf16) lives in 64 VGPRs.
// B-frags stream straight from L2 (no LDS, no __syncthreads in K-loop).
__global__ __launch_bounds__(64) void gemm_kernel(const float* __restrict__ x,
                                                  const float* __restrict__ embed,
                                                  const unsigned short* __restrict__ enb,
                                                  const float* __restrict__ inv_x,
                                                  float* __restrict__ out,
                                                  int* __restrict__ cnt1,
                                                  int* __restrict__ list1) {
    const int ln  = threadIdx.x;        // 0..63
    const int qd  = ln >> 4;
    const int l15 = ln & 15;

    // XCD swizzle: blocks with same q land on the same XCDs (codebook L2 reuse)
    const int bid  = blockIdx.x;                  // 0..2047
    const int q    = (bid & 7) >> 1;
    const int tile = ((bid >> 3) << 1) | (bid & 1);   // 0..511
    const int t0   = (tile >> 6) * Nq + q * Mq + (tile & 63) * 32;

    // ---- stage A in registers: 2 m-frags x 8 k-chunks, normalized bf16 -----
    bf16x8 a[2][8];
    #pragma unroll
    for (int mf = 0; mf < 2; ++mf) {
        int t = t0 + mf * 16 + l15;
        float sx = inv_x[t];
        const float* xr = x + (size_t)t * Dq + qd * 8;
        #pragma unroll
        for (int ch = 0; ch < 8; ++ch) {
            float4 u = *(const float4*)(xr + ch * 32);
            float4 v = *(const float4*)(xr + ch * 32 + 4);
            bf16x8 f;
            f[0] = (short)f2bf(u.x * sx); f[1] = (short)f2bf(u.y * sx);
            f[2] = (short)f2bf(u.z * sx); f[3] = (short)f2bf(u.w * sx);
            f[4] = (short)f2bf(v.x * sx); f[5] = (short)f2bf(v.y * sx);
            f[6] = (short)f2bf(v.z * sx); f[7] = (short)f2bf(v.w * sx);
            a[mf][ch] = f;
        }
    }

    // per-lane running top-2 for rows (qd*4+r) of each m-frag
    float b1[2][4], b2[2][4];
    int   ic[2][4];
    #pragma unroll
    for (int mf = 0; mf < 2; ++mf)
        #pragma unroll
        for (int r = 0; r < 4; ++r) { b1[mf][r] = -2.0f; b2[mf][r] = -2.0f; ic[mf][r] = 0; }

    // B base for this lane: code (cb + l15), dims qd*8 within each 32-chunk
    const unsigned short* ebase = enb + (size_t)q * Kq * Dq + (size_t)l15 * Dq + qd * 8;

#define LOADB(B, cb) do {                                                     \
        const unsigned short* _p = ebase + (size_t)(cb) * Dq;                 \
        B[0] = *(const bf16x8*)(_p);                                          \
        B[1] = *(const bf16x8*)(_p + 32);                                     \
        B[2] = *(const bf16x8*)(_p + 64);                                     \
        B[3] = *(const bf16x8*)(_p + 96);                                     \
        B[4] = *(const bf16x8*)(_p + 128);                                    \
        B[5] = *(const bf16x8*)(_p + 160);                                    \
        B[6] = *(const bf16x8*)(_p + 192);                                    \
        B[7] = *(const bf16x8*)(_p + 224);                                    \
    } while (0)

#define PROCESS(B, cb) do {                                                   \
        f32x4 ac0 = {0.f, 0.f, 0.f, 0.f};                                     \
        f32x4 ac1 = {0.f, 0.f, 0.f, 0.f};                                     \
        _Pragma("unroll")                                                     \
        for (int ch = 0; ch < 8; ++ch) {                                      \
            ac0 = __builtin_amdgcn_mfma_f32_16x16x32_bf16(a[0][ch], B[ch], ac0, 0, 0, 0); \
            ac1 = __builtin_amdgcn_mfma_f32_16x16x32_bf16(a[1][ch], B[ch], ac1, 0, 0, 0); \
        }                                                                     \
        int c = (cb) + l15;                                                   \
        _Pragma("unroll")                                                     \
        for (int r = 0; r < 4; ++r) {                                         \
            float s0 = ac0[r];                                                \
            if (s0 > b1[0][r]) { b2[0][r] = b1[0][r]; b1[0][r] = s0; ic[0][r] = c; } \
            else if (s0 > b2[0][r]) b2[0][r] = s0;                            \
            float s1 = ac1[r];                                                \
            if (s1 > b1[1][r]) { b2[1][r] = b1[1][r]; b1[1][r] = s1; ic[1][r] = c; } \
            else if (s1 > b2[1][r]) b2[1][r] = s1;                            \
        }                                                                     \
    } while (0)

    bf16x8 bbA[8], bbB[8];
    LOADB(bbA, 0);
    for (int it = 0; it < 64; ++it) {
        const int cbA = it * 32, cbB = cbA + 16;
        LOADB(bbB, cbB);
        PROCESS(bbA, cbA);
        LOADB(bbA, (it < 63) ? (cbA + 32) : 0);   // last load is a dummy (L2 hit)
        PROCESS(bbB, cbB);
    }

    // ---- 16-lane butterfly top-2 reduce (tie -> smaller code, first-max) ---
    float fb1[2][4], fb2[2][4];
    int   fic[2][4];
    #pragma unroll
    for (int mf = 0; mf < 2; ++mf)
        #pragma unroll
        for (int r = 0; r < 4; ++r) {
            float v1 = b1[mf][r], v2 = b2[mf][r]; int vi = ic[mf][r];
            #pragma unroll
            for (int m = 1; m < 16; m <<= 1) {
                float o1 = __shfl_xor(v1, m, 64);
                float o2 = __shfl_xor(v2, m, 64);
                int   oi = __shfl_xor(vi, m, 64);
                if (o1 > v1 || (o1 == v1 && oi < vi)) { v2 = fmaxf(v1, o2); v1 = o1; vi = oi; }
                else v2 = fmaxf(v2, o1);
            }
            fb1[mf][r] = v1; fb2[mf][r] = v2; fic[mf][r] = vi;
        }

    // encoding + flags (writer: l15==0 of each quad)
    if (l15 == 0) {
        #pragma unroll
        for (int mf = 0; mf < 2; ++mf)
            #pragma unroll
            for (int r = 0; r < 4; ++r) {
                int t = t0 + mf * 16 + qd * 4 + r;
                out[QUANT_ELEMS + (size_t)t] = (float)fic[mf][r];
                if (fb1[mf][r] - fb2[mf][r] < THRESH1) {
                    int pos = atomicAdd(&cnt1[q], 1);
                    if (pos < CAP1Q) list1[q * CAP1Q + pos] = t;
                }
            }
    }

    // gather raw embed rows: one full 1 KB row per wave-instruction
    const float* eqf = embed + (size_t)q * Kq * Dq;
    #pragma unroll
    for (int mf = 0; mf < 2; ++mf)
        #pragma unroll
        for (int r = 0; r < 4; ++r)
            #pragma unroll
            for (int g = 0; g < 4; ++g) {
                int code = __shfl(fic[mf][r], g * 16, 64);
                int t = t0 + mf * 16 + g * 4 + r;
                float4 v = *(const float4*)(eqf + (size_t)code * Dq + ln * 4);
                *(float4*)(out + (size_t)t * Dq + ln * 4) = v;
            }

    if (bid == 0 && ln == 0) out[QUANT_ELEMS + TT] = 0.0f;
}

// ---------------- stage 2: fp32 re-rank, 8 same-q tokens per block ----------
__global__ __launch_bounds__(256) void rerank_batch(const float* __restrict__ x,
                                                    const float* __restrict__ embed,
                                                    const float* __restrict__ inv_e,
                                                    const float* __restrict__ inv_x,
                                                    float* __restrict__ out,
                                                    const int* __restrict__ cnt1,
                                                    const int* __restrict__ list1,
                                                    int* __restrict__ cnt2,
                                                    int* __restrict__ list2) {
    __shared__ float xn[8][Dq];
    __shared__ float sb1[8][256], sb2[8][256];
    __shared__ int   sbi[8][256];
    __shared__ int   stok[8], skb[8], sac[8];
    const int tid = threadIdx.x;

    for (int q = 0; q < Qq; ++q) {
        int count = cnt1[q]; if (count > CAP1Q) count = CAP1Q;
        const float* eq   = embed + (size_t)q * Kq * Dq;
        const float* invq = inv_e + (size_t)q * Kq;
        for (int base = blockIdx.x * 8; base < count; base += gridDim.x * 8) {
            int nb = count - base; if (nb > 8) nb = 8;
            if (tid < 8) stok[tid] = list1[q * CAP1Q + base + (tid < nb ? tid : 0)];
            __syncthreads();
            {   // stage normalized x rows
                int i = tid >> 5, off = (tid & 31) * 8;
                int t = stok[i];
                float sx = inv_x[t];
                const float* xr = x + (size_t)t * Dq + off;
                float4 u = *(const float4*)(xr);
                float4 v = *(const float4*)(xr + 4);
                xn[i][off + 0] = u.x * sx; xn[i][off + 1] = u.y * sx;
                xn[i][off + 2] = u.z * sx; xn[i][off + 3] = u.w * sx;
                xn[i][off + 4] = v.x * sx; xn[i][off + 5] = v.y * sx;
                xn[i][off + 6] = v.z * sx; xn[i][off + 7] = v.w * sx;
            }
            __syncthreads();

            // 8 tokens x 8 codes register block; thread's codes = tid*8..+8
            float acc[8][8];
            #pragma unroll
            for (int i = 0; i < 8; ++i)
                #pragma unroll
                for (int j = 0; j < 8; ++j) acc[i][j] = 0.0f;

            for (int d = 0; d < Dq; d += 4) {
                float4 e[8], xv[8];
                #pragma unroll
                for (int j = 0; j < 8; ++j)
                    e[j] = *(const float4*)(eq + (size_t)(tid * 8 + j) * Dq + d);
                #pragma unroll
                for (int i = 0; i < 8; ++i)
                    xv[i] = *(const float4*)&xn[i][d];
                #pragma unroll
                for (int i = 0; i < 8; ++i)
                    #pragma unroll
                    for (int j = 0; j < 8; ++j) {
                        acc[i][j] = fmaf(xv[i].x, e[j].x, acc[i][j]);
                        acc[i][j] = fmaf(xv[i].y, e[j].y, acc[i][j]);
                        acc[i][j] = fmaf(xv[i].z, e[j].z, acc[i][j]);
                        acc[i][j] = fmaf(xv[i].w, e[j].w, acc[i][j]);
                    }
            }

            float tb1[8], tb2[8]; int tbi[8];
            #pragma unroll
            for (int i = 0; i < 8; ++i) { tb1[i] = -2.0f; tb2[i] = -2.0f; tbi[i] = 0; }
            #pragma unroll
            for (int j = 0; j < 8; ++j) {
                int k = tid * 8 + j;        // ascending within thread
                float iq = invq[k];
                #pragma unroll
                for (int i = 0; i < 8; ++i) {
                    float s = acc[i][j] * iq;
                    if (s > tb1[i]) { tb2[i] = tb1[i]; tb1[i] = s; tbi[i] = k; }
                    else if (s > tb2[i]) tb2[i] = s;
                }
            }
            #pragma unroll
            for (int i = 0; i < 8; ++i) {
                sb1[i][tid] = tb1[i]; sb2[i][tid] = tb2[i]; sbi[i][tid] = tbi[i];
            }
            __syncthreads();
            for (int off = 128; off; off >>= 1) {
                if (tid < off) {
                    #pragma unroll
                    for (int i = 0; i < 8; ++i) {
                        float o1 = sb1[i][tid + off], o2 = sb2[i][tid + off];
                        int   oi = sbi[i][tid + off];
                        float a1 = sb1[i][tid], a2 = sb2[i][tid];
                        int   ai = sbi[i][tid];
                        if (o1 > a1 || (o1 == a1 && oi < ai)) {
                            sb1[i][tid] = o1; sb2[i][tid] = fmaxf(a1, o2); sbi[i][tid] = oi;
                        } else {
                            sb2[i][tid] = fmaxf(a2, o1);
                        }
                    }
                }
                __syncthreads();
            }
            if (tid < 8) {
                sac[tid] = 0;
                if (tid < nb) {
                    int t = stok[tid];
                    if (sb1[tid][0] - sb2[tid][0] < THRESH2) {
                        int pos = atomicAdd(cnt2, 1);
                        if (pos < CAP2) list2[pos] = t;
                    } else {
                        out[QUANT_ELEMS + (size_t)t] = (float)sbi[tid][0];
                        skb[tid] = sbi[tid][0];
                        sac[tid] = 1;
                    }
                }
            }
            __syncthreads();
            #pragma unroll 1
            for (int i = 0; i < 8; ++i) {
                if (sac[i] && tid < 64) {
                    float4 v = *(const float4*)(eq + (size_t)skb[i] * Dq + tid * 4);
                    *(float4*)(out + (size_t)stok[i] * Dq + tid * 4) = v;
                }
            }
            __syncthreads();
        }
    }
}

// ---------------- numpy-fp32 emulation helpers ------------------------------
__device__ __forceinline__ float np_pw128_sq(const float* a) {
#pragma clang fp contract(off)
    float r[8];
    #pragma unroll
    for (int j = 0; j < 8; ++j) { float v = a[j]; r[j] = v * v; }
    for (int i = 8; i < 128; i += 8) {
        #pragma unroll
        for (int j = 0; j < 8; ++j) { float v = a[i + j]; r[j] = r[j] + v * v; }
    }
    return ((r[0] + r[1]) + (r[2] + r[3])) + ((r[4] + r[5]) + (r[6] + r[7]));
}
__device__ __forceinline__ float f32_div(float a, float b) {
    return (float)((double)a / (double)b);
}
__device__ __forceinline__ float np_norm256(const float* a) {
#pragma clang fp contract(off)
    float n2 = np_pw128_sq(a) + np_pw128_sq(a + 128);
    float nm = (float)sqrt((double)n2);
    return fmaxf(nm, 1e-12f);
}

// ---------------- stage 3: numpy-fp32-emulating re-rank ---------------------
__global__ __launch_bounds__(256) void fixup_np(const float* __restrict__ x,
                                                const float* __restrict__ embed,
                                                float* __restrict__ out,
                                                const int* __restrict__ cnt2,
                                                const int* __restrict__ list2) {
#pragma clang fp contract(off)
    __shared__ float xn[Dq];
    __shared__ float ssc[256];
    __shared__ int   sid[256];
    __shared__ float s_nm;
    int count = *cnt2; if (count > CAP2) count = CAP2;
    const int tid = threadIdx.x;

    for (int i = blockIdx.x; i < count; i += gridDim.x) {
        int t = list2[i];
        int q = (t % Nq) / Mq;
        const float* xr  = x + (size_t)t * Dq;
        const float* eqb = embed + (size_t)q * Kq * Dq;

        if (tid == 0) s_nm = np_norm256(xr);
        __syncthreads();
        xn[tid] = f32_div(xr[tid], s_nm);
        __syncthreads();

        float bs = -2.0f; int bk = 0;
        #pragma unroll 1
        for (int j = 0; j < 8; ++j) {
            int k = tid * 8 + j;
            const float* er = eqb + (size_t)k * Dq;
            float nme = np_norm256(er);
            float l0 = 0.0f, l1 = 0.0f, l2 = 0.0f, l3 = 0.0f;
            for (int d = 0; d < Dq; d += 4) {
                float e0 = f32_div(er[d + 0], nme);
                float e1 = f32_div(er[d + 1], nme);
                float e2 = f32_div(er[d + 2], nme);
                float e3 = f32_div(er[d + 3], nme);
                l0 = l0 + xn[d + 0] * e0;
                l1 = l1 + xn[d + 1] * e1;
                l2 = l2 + xn[d + 2] * e2;
                l3 = l3 + xn[d + 3] * e3;
            }
            float sc = (l0 + l1) + (l2 + l3);
            if (sc > bs) { bs = sc; bk = k; }
        }
        ssc[tid] = bs; sid[tid] = bk;
        __syncthreads();
        for (int off = 128; off; off >>= 1) {
            if (tid < off) {
                float os = ssc[tid + off]; int oi = sid[tid + off];
                if (os > ssc[tid] || (os == ssc[tid] && oi < sid[tid])) {
                    ssc[tid] = os; sid[tid] = oi;
                }
            }
            __syncthreads();
        }
        int kbest = sid[0];
        if (tid == 0) out[QUANT_ELEMS + (size_t)t] = (float)kbest;
        if (tid < 64) {
            float4 v = *(const float4*)(eqb + (size_t)kbest * Dq + tid * 4);
            *(float4*)(out + (size_t)t * Dq + tid * 4) = v;
        }
        __syncthreads();
    }
}

extern "C" void kernel_launch(void* const* d_in, const int* in_sizes, int n_in,
                              void* d_out, int out_size, void* d_ws, size_t ws_size,
                              hipStream_t stream) {
    const float* x     = (const float*)d_in[0];
    const float* embed = (const float*)d_in[1];
    float* out = (float*)d_out;
    char* ws = (char*)d_ws;
    float* inv_e = (float*)(ws + WS_INVE_OFF);
    float* inv_x = (float*)(ws + WS_INVX_OFF);
    int* cnt1  = (int*)(ws + WS_CNT_OFF);
    int* cnt2  = (int*)(ws + WS_CNT_OFF + 16);
    int* list1 = (int*)(ws + WS_LIST1_OFF);
    int* list2 = (int*)(ws + WS_LIST2_OFF);
    unsigned short* enb = (unsigned short*)(ws + WS_ENB_OFF);

    hipMemsetAsync(ws + WS_CNT_OFF, 0, 32, stream);
    norm_kernel<<<(Qq * Kq) / 4, 256, 0, stream>>>(embed, inv_e);
    norm_kernel<<<TT / 4, 256, 0, stream>>>(x, inv_x);
    cvt_kernel<<<(Qq * Kq) / 4, 256, 0, stream>>>(embed, inv_e, enb);
    gemm_kernel<<<TT / 32, 64, 0, stream>>>(x, embed, enb, inv_x, out, cnt1, list1);
    rerank_batch<<<512, 256, 0, stream>>>(x, embed, inv_e, inv_x, out,
                                          cnt1, list1, cnt2, list2);
    fixup_np<<<256, 256, 0, stream>>>(x, embed, out, cnt2, list2);
}

// Round 6
// 820.825 us; speedup vs baseline: 8.2370x; 1.1582x over previous
//
#include <hip/hip_runtime.h>
#include <math.h>

// Problem constants
#define Bq 8
#define Nq 8192
#define Dq 256
#define Qq 4
#define Kq 2048
#define Mq (Nq / Qq)
#define TT (Bq * Nq)                    // 65536 tokens
#define QUANT_ELEMS ((size_t)TT * Dq)   // 16777216

#define CAP 16384
#define THRESH 3e-4f        // fp16 margin band: ~8.6 sigma of measured-model error

// ws layout (bytes)
#define WS_CNT_OFF  0u
#define WS_LIST_OFF 16u
#define WS_ENH_OFF  65536u  // 4 MB fp16 normalized codes, tiled (32 codes) + XOR-swizzled

typedef __attribute__((ext_vector_type(8))) _Float16 f16x8;
typedef __attribute__((ext_vector_type(4))) _Float16 f16x4;
typedef __attribute__((ext_vector_type(4))) float    f32x4;

__device__ __forceinline__ void async_load16(const void* g, void* s) {
    __builtin_amdgcn_global_load_lds(
        (const __attribute__((address_space(1))) void*)g,
        (__attribute__((address_space(3))) void*)s, 16, 0, 0);
}

// ---------------- cvt: normalize codes -> fp16, tiled + swizzled ------------
// Layout: tile Tb = 32 codes. Block of 16 KB: row c (512 B), granule slot p
// holds logical granule g = p ^ c  (granule = 16 B = 8 dims).
__global__ __launch_bounds__(256) void cvt_kernel(const float* __restrict__ embed,
                                                  char* __restrict__ enh) {
    int row = blockIdx.x * 4 + (threadIdx.x >> 6);   // 0..8191
    int ln  = threadIdx.x & 63;
    float4 v = *(const float4*)(embed + (size_t)row * Dq + ln * 4);
    float s = v.x * v.x + v.y * v.y + v.z * v.z + v.w * v.w;
    #pragma unroll
    for (int m = 1; m < 64; m <<= 1) s += __shfl_xor(s, m, 64);
    float sx = 1.0f / fmaxf(sqrtf(s), 1e-12f);
    int q = row >> 11, k = row & 2047, Tb = k >> 5, c = k & 31;
    int g = ln >> 1, h = ln & 1;                     // granule, half (8 B)
    f16x4 o;
    o[0] = (_Float16)(v.x * sx); o[1] = (_Float16)(v.y * sx);
    o[2] = (_Float16)(v.z * sx); o[3] = (_Float16)(v.w * sx);
    char* dst = enh + ((size_t)(q * 64 + Tb)) * 16384 + c * 512 + ((g ^ c) << 4) + h * 8;
    *(f16x4*)dst = o;
}

// ---------------- stage 1: LDS-shared-B fp16 MFMA scoring + top-2 + gather --
// Block = 4 waves x 32 tokens = 128 tokens. B: 32-code tiles, double-buffered
// LDS via global_load_lds, shared by all 4 waves. A register-resident.
__global__ __launch_bounds__(256) void gemm_kernel(const float* __restrict__ x,
                                                   const float* __restrict__ embed,
                                                   const char* __restrict__ enh,
                                                   float* __restrict__ out,
                                                   int* __restrict__ cnt,
                                                   int* __restrict__ list) {
    __shared__ __align__(16) char es[2][16384];

    const int tid = threadIdx.x;
    const int wv  = tid >> 6;
    const int ln  = tid & 63;
    const int qd  = ln >> 4;
    const int l15 = ln & 15;

    // XCD pinning: q = bid&3 -> each XCD (bid%8) sees exactly one codebook
    const int bid = blockIdx.x;              // 0..511
    const int q   = bid & 3;
    const int w   = bid >> 2;                // 0..127
    const int t0  = (w >> 4) * Nq + q * Mq + (w & 15) * 128;
    const int t0w = t0 + wv * 32;

    // ---- stage A in regs: 32 tokens, normalize (scale cancels in argmax) ---
    f16x8 ah[2][8];
    #pragma unroll
    for (int mf = 0; mf < 2; ++mf) {
        const float* xr = x + (size_t)(t0w + mf * 16 + l15) * Dq + qd * 8;
        float4 xa[16];
        float s2 = 0.f;
        #pragma unroll
        for (int ch = 0; ch < 8; ++ch) {
            float4 u = *(const float4*)(xr + ch * 32);
            float4 v = *(const float4*)(xr + ch * 32 + 4);
            xa[2 * ch] = u; xa[2 * ch + 1] = v;
            s2 += u.x * u.x + u.y * u.y + u.z * u.z + u.w * u.w;
            s2 += v.x * v.x + v.y * v.y + v.z * v.z + v.w * v.w;
        }
        s2 += __shfl_xor(s2, 16, 64);       // sum the 4 quads of this row
        s2 += __shfl_xor(s2, 32, 64);
        float sx = 1.0f / fmaxf(sqrtf(s2), 1e-12f);
        #pragma unroll
        for (int ch = 0; ch < 8; ++ch) {
            float4 u = xa[2 * ch], v = xa[2 * ch + 1];
            f16x8 f;
            f[0] = (_Float16)(u.x * sx); f[1] = (_Float16)(u.y * sx);
            f[2] = (_Float16)(u.z * sx); f[3] = (_Float16)(u.w * sx);
            f[4] = (_Float16)(v.x * sx); f[5] = (_Float16)(v.y * sx);
            f[6] = (_Float16)(v.z * sx); f[7] = (_Float16)(v.w * sx);
            ah[mf][ch] = f;
        }
    }

    float b1[2][4], b2[2][4];
    int   ic[2][4];
    #pragma unroll
    for (int mf = 0; mf < 2; ++mf)
        #pragma unroll
        for (int r = 0; r < 4; ++r) { b1[mf][r] = -2.0f; b2[mf][r] = -2.0f; ic[mf][r] = 0; }

    const char* ebase = enh + ((size_t)q * 64) * 16384;

    // prologue: stage tile 0
    #pragma unroll
    for (int i = 0; i < 4; ++i) {
        int off = i * 4096 + wv * 1024 + ln * 16;
        async_load16(ebase + off, es[0] + off);
    }
    __syncthreads();

    for (int T = 0; T < 64; ++T) {
        // prefetch next tile into the other buffer
        if (T + 1 < 64) {
            const char* src = ebase + (size_t)(T + 1) * 16384;
            #pragma unroll
            for (int i = 0; i < 4; ++i) {
                int off = i * 4096 + wv * 1024 + ln * 16;
                async_load16(src + off, es[(T + 1) & 1] + off);
            }
        }
        const char* esb = es[T & 1];

        #pragma unroll
        for (int s = 0; s < 2; ++s) {
            const int  c  = s * 16 + l15;             // code within tile
            const char* cb = esb + c * 512;
            f16x8 bfr[8];
            #pragma unroll
            for (int ch = 0; ch < 8; ++ch)
                bfr[ch] = *(const f16x8*)(cb + ((((ch << 2) | qd) ^ c) << 4));

            f32x4 a0 = {0.f, 0.f, 0.f, 0.f};
            f32x4 a1 = {0.f, 0.f, 0.f, 0.f};
            #pragma unroll
            for (int ch = 0; ch < 8; ++ch) {
                a0 = __builtin_amdgcn_mfma_f32_16x16x32_f16(ah[0][ch], bfr[ch], a0, 0, 0, 0);
                a1 = __builtin_amdgcn_mfma_f32_16x16x32_f16(ah[1][ch], bfr[ch], a1, 0, 0, 0);
            }
            const int cg = (T << 5) + (s << 4) + l15;  // global code
            #pragma unroll
            for (int r = 0; r < 4; ++r) {
                float s0 = a0[r];
                if (s0 > b1[0][r]) { b2[0][r] = b1[0][r]; b1[0][r] = s0; ic[0][r] = cg; }
                else if (s0 > b2[0][r]) b2[0][r] = s0;
                float s1 = a1[r];
                if (s1 > b1[1][r]) { b2[1][r] = b1[1][r]; b1[1][r] = s1; ic[1][r] = cg; }
                else if (s1 > b2[1][r]) b2[1][r] = s1;
            }
        }
        __syncthreads();   // waves done with es[T&1]; prefetch (T+1) drained
    }

    // ---- 16-lane butterfly top-2 reduce (tie -> smaller code, first-max) ---
    float fb1[2][4], fb2[2][4];
    int   fic[2][4];
    #pragma unroll
    for (int mf = 0; mf < 2; ++mf)
        #pragma unroll
        for (int r = 0; r < 4; ++r) {
            float v1 = b1[mf][r], v2 = b2[mf][r]; int vi = ic[mf][r];
            #pragma unroll
            for (int m = 1; m < 16; m <<= 1) {
                float o1 = __shfl_xor(v1, m, 64);
                float o2 = __shfl_xor(v2, m, 64);
                int   oi = __shfl_xor(vi, m, 64);
                if (o1 > v1 || (o1 == v1 && oi < vi)) { v2 = fmaxf(v1, o2); v1 = o1; vi = oi; }
                else v2 = fmaxf(v2, o1);
            }
            fb1[mf][r] = v1; fb2[mf][r] = v2; fic[mf][r] = vi;
        }

    // encoding + flags
    if (l15 == 0) {
        #pragma unroll
        for (int mf = 0; mf < 2; ++mf)
            #pragma unroll
            for (int r = 0; r < 4; ++r) {
                int t = t0w + mf * 16 + qd * 4 + r;
                out[QUANT_ELEMS + (size_t)t] = (float)fic[mf][r];
                if (fb1[mf][r] - fb2[mf][r] < THRESH) {
                    int pos = atomicAdd(cnt, 1);
                    if (pos < CAP) list[pos] = t;
                }
            }
    }

    // gather raw embed rows (1 KB row per wave-instruction)
    const float* eqf = embed + (size_t)q * Kq * Dq;
    #pragma unroll
    for (int mf = 0; mf < 2; ++mf)
        #pragma unroll
        for (int r = 0; r < 4; ++r)
            #pragma unroll
            for (int g = 0; g < 4; ++g) {
                int code = __shfl(fic[mf][r], g * 16, 64);
                int t = t0w + mf * 16 + g * 4 + r;
                float4 v = *(const float4*)(eqf + (size_t)code * Dq + ln * 4);
                *(float4*)(out + (size_t)t * Dq + ln * 4) = v;
            }

    if (bid == 0 && tid == 0) out[QUANT_ELEMS + TT] = 0.0f;   // vq_loss
}

// ---------------- numpy-fp32 emulation helpers ------------------------------
__device__ __forceinline__ float np_pw128_sq(const float* a) {
#pragma clang fp contract(off)
    float r[8];
    #pragma unroll
    for (int j = 0; j < 8; ++j) { float v = a[j]; r[j] = v * v; }
    for (int i = 8; i < 128; i += 8) {
        #pragma unroll
        for (int j = 0; j < 8; ++j) { float v = a[i + j]; r[j] = r[j] + v * v; }
    }
    return ((r[0] + r[1]) + (r[2] + r[3])) + ((r[4] + r[5]) + (r[6] + r[7]));
}
__device__ __forceinline__ float f32_div(float a, float b) {
    return (float)((double)a / (double)b);
}
__device__ __forceinline__ float np_norm256(const float* a) {
#pragma clang fp contract(off)
    float n2 = np_pw128_sq(a) + np_pw128_sq(a + 128);
    float nm = (float)sqrt((double)n2);
    return fmaxf(nm, 1e-12f);
}

// ---------------- stage 2: numpy-fp32-emulating exact re-rank ---------------
__global__ __launch_bounds__(256) void fixup_np(const float* __restrict__ x,
                                                const float* __restrict__ embed,
                                                float* __restrict__ out,
                                                const int* __restrict__ cnt,
                                                const int* __restrict__ list) {
#pragma clang fp contract(off)
    __shared__ float xn[Dq];
    __shared__ float ssc[256];
    __shared__ int   sid[256];
    __shared__ float s_nm;
    int count = *cnt; if (count > CAP) count = CAP;
    const int tid = threadIdx.x;

    for (int i = blockIdx.x; i < count; i += gridDim.x) {
        int t = list[i];
        int q = (t % Nq) / Mq;
        const float* xr  = x + (size_t)t * Dq;
        const float* eqb = embed + (size_t)q * Kq * Dq;

        if (tid == 0) s_nm = np_norm256(xr);
        __syncthreads();
        xn[tid] = f32_div(xr[tid], s_nm);
        __syncthreads();

        float bs = -2.0f; int bk = 0;
        #pragma unroll 1
        for (int j = 0; j < 8; ++j) {
            int k = tid * 8 + j;                    // ascending within thread
            const float* er = eqb + (size_t)k * Dq;
            float nme = np_norm256(er);
            float l0 = 0.0f, l1 = 0.0f, l2 = 0.0f, l3 = 0.0f;
            for (int d = 0; d < Dq; d += 4) {
                float e0 = f32_div(er[d + 0], nme);
                float e1 = f32_div(er[d + 1], nme);
                float e2 = f32_div(er[d + 2], nme);
                float e3 = f32_div(er[d + 3], nme);
                l0 = l0 + xn[d + 0] * e0;
                l1 = l1 + xn[d + 1] * e1;
                l2 = l2 + xn[d + 2] * e2;
                l3 = l3 + xn[d + 3] * e3;
            }
            float sc = (l0 + l1) + (l2 + l3);
            if (sc > bs) { bs = sc; bk = k; }
        }
        ssc[tid] = bs; sid[tid] = bk;
        __syncthreads();
        for (int off = 128; off; off >>= 1) {
            if (tid < off) {
                float os = ssc[tid + off]; int oi = sid[tid + off];
                if (os > ssc[tid] || (os == ssc[tid] && oi < sid[tid])) {
                    ssc[tid] = os; sid[tid] = oi;
                }
            }
            __syncthreads();
        }
        int kbest = sid[0];
        if (tid == 0) out[QUANT_ELEMS + (size_t)t] = (float)kbest;
        if (tid < 64) {
            float4 v = *(const float4*)(eqb + (size_t)kbest * Dq + tid * 4);
            *(float4*)(out + (size_t)t * Dq + tid * 4) = v;
        }
        __syncthreads();
    }
}

extern "C" void kernel_launch(void* const* d_in, const int* in_sizes, int n_in,
                              void* d_out, int out_size, void* d_ws, size_t ws_size,
                              hipStream_t stream) {
    const float* x     = (const float*)d_in[0];
    const float* embed = (const float*)d_in[1];
    float* out = (float*)d_out;
    char*  ws  = (char*)d_ws;
    int*  cnt  = (int*)(ws + WS_CNT_OFF);
    int*  list = (int*)(ws + WS_LIST_OFF);
    char* enh  = ws + WS_ENH_OFF;

    hipMemsetAsync(cnt, 0, 16, stream);
    cvt_kernel<<<(Qq * Kq) / 4, 256, 0, stream>>>(embed, enh);
    gemm_kernel<<<512, 256, 0, stream>>>(x, embed, enh, out, cnt, list);
    fixup_np<<<1024, 256, 0, stream>>>(x, embed, out, cnt, list);
}

// Round 7
// 298.574 us; speedup vs baseline: 22.6447x; 2.7491x over previous
//
#include <hip/hip_runtime.h>
#include <math.h>

// Problem constants
#define Bq 8
#define Nq 8192
#define Dq 256
#define Qq 4
#define Kq 2048
#define Mq (Nq / Qq)
#define TT (Bq * Nq)                    // 65536 tokens
#define QUANT_ELEMS ((size_t)TT * Dq)   // 16777216

#define CAP1Q 4096
#define THRESH 3e-4f        // fp16 margin band (~12 sigma of fp16-input score error)

// ws layout (bytes)
#define WS_CNT_OFF    0u
#define WS_LIST_OFF   1024u      // 4*4096 ints  = 64 KB   -> [1024, 66560)
#define WS_PSC_OFF    66560u     // 4*4096*8 f32 = 512 KB  -> [66560, 590848)
#define WS_PCD_OFF    590848u    // 4*4096*8 i32 = 512 KB  -> [590848, 1115136)
#define WS_ENH_OFF    1115136u   // 4 MB fp16 swizzled codes
#define WS_ENP_OFF    5309440u   // 8 MB fp32 numpy-normalized codes

typedef __attribute__((ext_vector_type(8))) _Float16 f16x8;
typedef __attribute__((ext_vector_type(4))) _Float16 f16x4;
typedef __attribute__((ext_vector_type(4))) float    f32x4;

__device__ __forceinline__ void async_load16(const void* g, void* s) {
    __builtin_amdgcn_global_load_lds(
        (const __attribute__((address_space(1))) void*)g,
        (__attribute__((address_space(3))) void*)s, 16, 0, 0);
}

__device__ __forceinline__ float f32_div(float a, float b) {
    return (float)((double)a / (double)b);   // exact IEEE fp32 divide
}

// numpy pairwise norm of a 256-row, wave-parallel but BIT-EXACT vs the serial
// 8-accumulator + tree emulation (validated round 3). Lanes 0..15 active.
__device__ __forceinline__ float np_norm_wave(const float* __restrict__ src, int ln) {
#pragma clang fp contract(off)
    float r = 0.0f;
    if (ln < 16) {
        const float* p = src + (ln >> 3) * 128 + (ln & 7);
        #pragma unroll
        for (int m = 0; m < 16; ++m) { float v = p[m * 8]; r = r + v * v; }
    }
    float t = r + __shfl_xor(r, 1, 64);      // (r0+r1) ...
    t = t + __shfl_xor(t, 2, 64);            // (r0+r1)+(r2+r3) ...
    t = t + __shfl_xor(t, 4, 64);            // full 8-acc tree
    float b0 = __shfl(t, 0, 64);
    float b1 = __shfl(t, 8, 64);
    float n2 = b0 + b1;                      // pw(0:128) + pw(128:256)
    return fmaxf((float)sqrt((double)n2), 1e-12f);
}

// ---------------- cvt: normalize codes -> fp16, tiled + swizzled ------------
__global__ __launch_bounds__(256) void cvt_kernel(const float* __restrict__ embed,
                                                  char* __restrict__ enh) {
    int row = blockIdx.x * 4 + (threadIdx.x >> 6);   // 0..8191
    int ln  = threadIdx.x & 63;
    float4 v = *(const float4*)(embed + (size_t)row * Dq + ln * 4);
    float s = v.x * v.x + v.y * v.y + v.z * v.z + v.w * v.w;
    #pragma unroll
    for (int m = 1; m < 64; m <<= 1) s += __shfl_xor(s, m, 64);
    float sx = 1.0f / fmaxf(sqrtf(s), 1e-12f);
    int q = row >> 11, k = row & 2047, Tb = k >> 5, c = k & 31;
    int g = ln >> 1, h = ln & 1;
    f16x4 o;
    o[0] = (_Float16)(v.x * sx); o[1] = (_Float16)(v.y * sx);
    o[2] = (_Float16)(v.z * sx); o[3] = (_Float16)(v.w * sx);
    char* dst = enh + ((size_t)(q * 64 + Tb)) * 16384 + c * 512 + ((g ^ c) << 4) + h * 8;
    *(f16x4*)dst = o;
}

// ---------------- enp: numpy-rounded normalized codebook (fp32) -------------
__global__ __launch_bounds__(256) void enp_kernel(const float* __restrict__ embed,
                                                  float* __restrict__ enp) {
    int row = blockIdx.x * 4 + (threadIdx.x >> 6);   // 0..8191
    int ln  = threadIdx.x & 63;
    const float* src = embed + (size_t)row * Dq;
    float nm = np_norm_wave(src, ln);
    float* dst = enp + (size_t)row * Dq;
    #pragma unroll
    for (int e = 0; e < 4; ++e) dst[ln * 4 + e] = f32_div(src[ln * 4 + e], nm);
}

// ---------------- stage 1: LDS-shared-B fp16 MFMA scoring (unchanged) -------
__global__ __launch_bounds__(256) void gemm_kernel(const float* __restrict__ x,
                                                   const float* __restrict__ embed,
                                                   const char* __restrict__ enh,
                                                   float* __restrict__ out,
                                                   int* __restrict__ cnt,
                                                   int* __restrict__ list) {
    __shared__ __align__(16) char es[2][16384];

    const int tid = threadIdx.x;
    const int wv  = tid >> 6;
    const int ln  = tid & 63;
    const int qd  = ln >> 4;
    const int l15 = ln & 15;

    const int bid = blockIdx.x;              // 0..511
    const int q   = bid & 3;
    const int w   = bid >> 2;
    const int t0  = (w >> 4) * Nq + q * Mq + (w & 15) * 128;
    const int t0w = t0 + wv * 32;

    f16x8 ah[2][8];
    #pragma unroll
    for (int mf = 0; mf < 2; ++mf) {
        const float* xr = x + (size_t)(t0w + mf * 16 + l15) * Dq + qd * 8;
        float4 xa[16];
        float s2 = 0.f;
        #pragma unroll
        for (int ch = 0; ch < 8; ++ch) {
            float4 u = *(const float4*)(xr + ch * 32);
            float4 v = *(const float4*)(xr + ch * 32 + 4);
            xa[2 * ch] = u; xa[2 * ch + 1] = v;
            s2 += u.x * u.x + u.y * u.y + u.z * u.z + u.w * u.w;
            s2 += v.x * v.x + v.y * v.y + v.z * v.z + v.w * v.w;
        }
        s2 += __shfl_xor(s2, 16, 64);
        s2 += __shfl_xor(s2, 32, 64);
        float sx = 1.0f / fmaxf(sqrtf(s2), 1e-12f);
        #pragma unroll
        for (int ch = 0; ch < 8; ++ch) {
            float4 u = xa[2 * ch], v = xa[2 * ch + 1];
            f16x8 f;
            f[0] = (_Float16)(u.x * sx); f[1] = (_Float16)(u.y * sx);
            f[2] = (_Float16)(u.z * sx); f[3] = (_Float16)(u.w * sx);
            f[4] = (_Float16)(v.x * sx); f[5] = (_Float16)(v.y * sx);
            f[6] = (_Float16)(v.z * sx); f[7] = (_Float16)(v.w * sx);
            ah[mf][ch] = f;
        }
    }

    float b1[2][4], b2[2][4];
    int   ic[2][4];
    #pragma unroll
    for (int mf = 0; mf < 2; ++mf)
        #pragma unroll
        for (int r = 0; r < 4; ++r) { b1[mf][r] = -2.0f; b2[mf][r] = -2.0f; ic[mf][r] = 0; }

    const char* ebase = enh + ((size_t)q * 64) * 16384;

    #pragma unroll
    for (int i = 0; i < 4; ++i) {
        int off = i * 4096 + wv * 1024 + ln * 16;
        async_load16(ebase + off, es[0] + off);
    }
    __syncthreads();

    for (int T = 0; T < 64; ++T) {
        if (T + 1 < 64) {
            const char* src = ebase + (size_t)(T + 1) * 16384;
            #pragma unroll
            for (int i = 0; i < 4; ++i) {
                int off = i * 4096 + wv * 1024 + ln * 16;
                async_load16(src + off, es[(T + 1) & 1] + off);
            }
        }
        const char* esb = es[T & 1];

        #pragma unroll
        for (int s = 0; s < 2; ++s) {
            const int  c  = s * 16 + l15;
            const char* cb = esb + c * 512;
            f16x8 bfr[8];
            #pragma unroll
            for (int ch = 0; ch < 8; ++ch)
                bfr[ch] = *(const f16x8*)(cb + ((((ch << 2) | qd) ^ c) << 4));

            f32x4 a0 = {0.f, 0.f, 0.f, 0.f};
            f32x4 a1 = {0.f, 0.f, 0.f, 0.f};
            #pragma unroll
            for (int ch = 0; ch < 8; ++ch) {
                a0 = __builtin_amdgcn_mfma_f32_16x16x32_f16(ah[0][ch], bfr[ch], a0, 0, 0, 0);
                a1 = __builtin_amdgcn_mfma_f32_16x16x32_f16(ah[1][ch], bfr[ch], a1, 0, 0, 0);
            }
            const int cg = (T << 5) + (s << 4) + l15;
            #pragma unroll
            for (int r = 0; r < 4; ++r) {
                float s0 = a0[r];
                if (s0 > b1[0][r]) { b2[0][r] = b1[0][r]; b1[0][r] = s0; ic[0][r] = cg; }
                else if (s0 > b2[0][r]) b2[0][r] = s0;
                float s1 = a1[r];
                if (s1 > b1[1][r]) { b2[1][r] = b1[1][r]; b1[1][r] = s1; ic[1][r] = cg; }
                else if (s1 > b2[1][r]) b2[1][r] = s1;
            }
        }
        __syncthreads();
    }

    float fb1[2][4], fb2[2][4];
    int   fic[2][4];
    #pragma unroll
    for (int mf = 0; mf < 2; ++mf)
        #pragma unroll
        for (int r = 0; r < 4; ++r) {
            float v1 = b1[mf][r], v2 = b2[mf][r]; int vi = ic[mf][r];
            #pragma unroll
            for (int m = 1; m < 16; m <<= 1) {
                float o1 = __shfl_xor(v1, m, 64);
                float o2 = __shfl_xor(v2, m, 64);
                int   oi = __shfl_xor(vi, m, 64);
                if (o1 > v1 || (o1 == v1 && oi < vi)) { v2 = fmaxf(v1, o2); v1 = o1; vi = oi; }
                else v2 = fmaxf(v2, o1);
            }
            fb1[mf][r] = v1; fb2[mf][r] = v2; fic[mf][r] = vi;
        }

    if (l15 == 0) {
        #pragma unroll
        for (int mf = 0; mf < 2; ++mf)
            #pragma unroll
            for (int r = 0; r < 4; ++r) {
                int t = t0w + mf * 16 + qd * 4 + r;
                out[QUANT_ELEMS + (size_t)t] = (float)fic[mf][r];
                if (fb1[mf][r] - fb2[mf][r] < THRESH) {
                    int pos = atomicAdd(&cnt[q], 1);
                    if (pos < CAP1Q) list[q * CAP1Q + pos] = t;
                }
            }
    }

    const float* eqf = embed + (size_t)q * Kq * Dq;
    #pragma unroll
    for (int mf = 0; mf < 2; ++mf)
        #pragma unroll
        for (int r = 0; r < 4; ++r)
            #pragma unroll
            for (int g = 0; g < 4; ++g) {
                int code = __shfl(fic[mf][r], g * 16, 64);
                int t = t0w + mf * 16 + g * 4 + r;
                float4 v = *(const float4*)(eqf + (size_t)code * Dq + ln * 4);
                *(float4*)(out + (size_t)t * Dq + ln * 4) = v;
            }

    if (bid == 0 && tid == 0) out[QUANT_ELEMS + TT] = 0.0f;
}

// ---------------- stage 2a: exact partial argmax, 16 tokens x 256 codes -----
__global__ __launch_bounds__(256) void fix_partial(const float* __restrict__ x,
                                                   const float* __restrict__ enp,
                                                   const int* __restrict__ cnt,
                                                   const int* __restrict__ list,
                                                   float* __restrict__ pscore,
                                                   int* __restrict__ pcode) {
#pragma clang fp contract(off)
    __shared__ float xn[16][Dq];
    __shared__ int   stok[16];
    __shared__ float wp_s[4][16];
    __shared__ int   wp_c[4][16];

    const int tid = threadIdx.x;
    const int wv  = tid >> 6;
    const int ln  = tid & 63;

    int cq[4], nbq[4], total = 0;
    #pragma unroll
    for (int q = 0; q < 4; ++q) {
        int c = cnt[q]; if (c > CAP1Q) c = CAP1Q;
        cq[q] = c; nbq[q] = (c + 15) >> 4; total += nbq[q] * 8;
    }

    for (int j = blockIdx.x; j < total; j += gridDim.x) {
        int rem = j, q = 0;
        while (rem >= nbq[q] * 8) { rem -= nbq[q] * 8; ++q; }
        const int batch = rem >> 3, chunk = rem & 7;

        if (tid < 16) {
            int idx = batch * 16 + tid;
            stok[tid] = list[q * CAP1Q + (idx < cq[q] ? idx : batch * 16)];
        }
        __syncthreads();
        // stage numpy-normalized x rows (wave handles 4 rows)
        for (int r = 0; r < 4; ++r) {
            int i = wv * 4 + r;
            const float* xr = x + (size_t)stok[i] * Dq;
            float nm = np_norm_wave(xr, ln);
            #pragma unroll
            for (int e = 0; e < 4; ++e)
                xn[i][ln * 4 + e] = f32_div(xr[ln * 4 + e], nm);
        }
        __syncthreads();

        const int c = chunk * 256 + tid;
        const float* er = enp + ((size_t)(q * Kq + c)) * Dq;
        float l0[16], l1[16], l2[16], l3[16];
        #pragma unroll
        for (int i = 0; i < 16; ++i) { l0[i] = 0.f; l1[i] = 0.f; l2[i] = 0.f; l3[i] = 0.f; }

        for (int d = 0; d < Dq; d += 4) {
            float4 e = *(const float4*)(er + d);
            #pragma unroll
            for (int i = 0; i < 16; ++i) {
                float4 xv = *(const float4*)&xn[i][d];   // wave-broadcast LDS read
                l0[i] = l0[i] + xv.x * e.x;
                l1[i] = l1[i] + xv.y * e.y;
                l2[i] = l2[i] + xv.z * e.z;
                l3[i] = l3[i] + xv.w * e.w;
            }
        }

        #pragma unroll
        for (int i = 0; i < 16; ++i) {
            float s = (l0[i] + l1[i]) + (l2[i] + l3[i]);   // numpy SSE tree
            int bc = c;
            #pragma unroll
            for (int m = 1; m < 64; m <<= 1) {
                float os = __shfl_xor(s, m, 64);
                int   oc = __shfl_xor(bc, m, 64);
                if (os > s || (os == s && oc < bc)) { s = os; bc = oc; }
            }
            if (ln == 0) { wp_s[wv][i] = s; wp_c[wv][i] = bc; }
        }
        __syncthreads();
        if (tid < 16) {
            int idx = batch * 16 + tid;
            if (idx < cq[q]) {
                float s = wp_s[0][tid]; int bc = wp_c[0][tid];
                #pragma unroll
                for (int w2 = 1; w2 < 4; ++w2) {
                    float os = wp_s[w2][tid]; int oc = wp_c[w2][tid];
                    if (os > s || (os == s && oc < bc)) { s = os; bc = oc; }
                }
                int p = q * CAP1Q + idx;
                pscore[p * 8 + chunk] = s;
                pcode[p * 8 + chunk]  = bc;
            }
        }
        __syncthreads();
    }
}

// ---------------- stage 2b: merge partials, write encoding + row ------------
__global__ __launch_bounds__(256) void fix_final(const float* __restrict__ embed,
                                                 const int* __restrict__ cnt,
                                                 const int* __restrict__ list,
                                                 const float* __restrict__ pscore,
                                                 const int* __restrict__ pcode,
                                                 float* __restrict__ out) {
    int cq[4], tot = 0;
    #pragma unroll
    for (int q = 0; q < 4; ++q) {
        int c = cnt[q]; if (c > CAP1Q) c = CAP1Q;
        cq[q] = c; tot += c;
    }
    const int wv = threadIdx.x >> 6, ln = threadIdx.x & 63;

    for (int j = blockIdx.x * 4 + wv; j < tot; j += gridDim.x * 4) {
        int rem = j, q = 0;
        while (rem >= cq[q]) { rem -= cq[q]; ++q; }
        int p = q * CAP1Q + rem;
        int t = list[p];
        int bc = 0;
        if (ln == 0) {
            float bs = pscore[p * 8]; bc = pcode[p * 8];
            #pragma unroll
            for (int ch = 1; ch < 8; ++ch) {
                float s = pscore[p * 8 + ch]; int c2 = pcode[p * 8 + ch];
                if (s > bs || (s == bs && c2 < bc)) { bs = s; bc = c2; }
            }
            out[QUANT_ELEMS + (size_t)t] = (float)bc;
        }
        bc = __shfl(bc, 0, 64);
        const float* er = embed + ((size_t)(q * Kq + bc)) * Dq;
        float4 v = *(const float4*)(er + ln * 4);
        *(float4*)(out + (size_t)t * Dq + ln * 4) = v;
    }
}

extern "C" void kernel_launch(void* const* d_in, const int* in_sizes, int n_in,
                              void* d_out, int out_size, void* d_ws, size_t ws_size,
                              hipStream_t stream) {
    const float* x     = (const float*)d_in[0];
    const float* embed = (const float*)d_in[1];
    float* out = (float*)d_out;
    char*  ws  = (char*)d_ws;
    int*   cnt    = (int*)(ws + WS_CNT_OFF);
    int*   list   = (int*)(ws + WS_LIST_OFF);
    float* pscore = (float*)(ws + WS_PSC_OFF);
    int*   pcode  = (int*)(ws + WS_PCD_OFF);
    char*  enh    = ws + WS_ENH_OFF;
    float* enp    = (float*)(ws + WS_ENP_OFF);

    hipMemsetAsync(cnt, 0, 16, stream);
    cvt_kernel<<<(Qq * Kq) / 4, 256, 0, stream>>>(embed, enh);
    enp_kernel<<<(Qq * Kq) / 4, 256, 0, stream>>>(embed, enp);
    gemm_kernel<<<512, 256, 0, stream>>>(x, embed, enh, out, cnt, list);
    fix_partial<<<1024, 256, 0, stream>>>(x, enp, cnt, list, pscore, pcode);
    fix_final<<<256, 256, 0, stream>>>(embed, cnt, list, pscore, pcode, out);
}